// Round 6
// baseline (154.567 us; speedup 1.0000x reference)
//
#include <hip/hip_runtime.h>

typedef unsigned short u16;
typedef unsigned int   u32;
typedef __attribute__((ext_vector_type(8))) short bf8_t;   // 8 bf16 (4 VGPR)
typedef __attribute__((ext_vector_type(4))) float f4_t;
typedef __attribute__((ext_vector_type(16))) float f16v;   // 32x32 acc

#define SEQ   1024
#define NH    16
#define DH    128
#define BATCH 4
#define MROWS 4096      // BATCH*SEQ
#define FDIM  2048      // NH*DH

__device__ __forceinline__ u16 f2bf(float f) {
  union { float f; u32 u; } v; v.f = f;
  u32 u = v.u;
  u += 0x7fffu + ((u >> 16) & 1u);   // RNE
  return (u16)(u >> 16);
}
__device__ __forceinline__ u32 cvtpk(float a, float b) {
  u32 r; asm("v_cvt_pk_bf16_f32 %0, %1, %2" : "=v"(r) : "v"(a), "v"(b)); return r;
}
__device__ __forceinline__ bf8_t mk8(u32 a, u32 b, u32 c, u32 d) {
  union { u32 u[4]; bf8_t v; } x; x.u[0] = a; x.u[1] = b; x.u[2] = c; x.u[3] = d; return x.v;
}

// ---------------- kernel P: fp32 -> bf16 pre-conversion --------------------
__global__ __launch_bounds__(256) void to_bf16(
    const float* __restrict__ x,  const float* __restrict__ wq,
    const float* __restrict__ wk, const float* __restrict__ wv,
    const float* __restrict__ wo,
    u16* __restrict__ xb, u16* __restrict__ wqb, u16* __restrict__ wkb,
    u16* __restrict__ wvb, u16* __restrict__ wob) {
  int i = blockIdx.x * 256 + threadIdx.x;   // 0..196607
  const float* s; u16* d; int o;
  if      (i <  65536) { s = x;  d = xb;  o = i; }
  else if (i <  98304) { s = wq; d = wqb; o = i - 65536; }
  else if (i < 131072) { s = wk; d = wkb; o = i - 98304; }
  else if (i < 163840) { s = wv; d = wvb; o = i - 131072; }
  else                 { s = wo; d = wob; o = i - 163840; }
  const f4_t* sp = reinterpret_cast<const f4_t*>(s + (size_t)o * 8);
  f4_t a = sp[0], b = sp[1];
  bf8_t pk;
#pragma unroll
  for (int j = 0; j < 4; ++j) { pk[j] = (short)f2bf(a[j]); pk[4 + j] = (short)f2bf(b[j]); }
  *reinterpret_cast<bf8_t*>(d + (size_t)o * 8) = pk;
}

// ---------------- kernel 0: RoPE tables ------------------------------------
__global__ __launch_bounds__(256) void rope_tables(float* __restrict__ cosT,
                                                   float* __restrict__ sinT) {
  int i = blockIdx.x * 256 + threadIdx.x;      // 65536 = 1024*64
  int s = i >> 6, p = i & 63;
  float ef = (float)(2 * p) / 128.0f;
  float angf = (float)pow(10000.0, (double)ef);
  float thf  = (float)s * angf;
  double th  = (double)thf;
  cosT[i] = (float)cos(th);
  sinT[i] = (float)sin(th);
}

// ---------------- kernel A: fused QKV projection + RoPE --------------------
// q,k: RoPE'd, [bh][s][d].  v: written TRANSPOSED to vT_g[bh][dv][s].
__global__ __launch_bounds__(256) void qkv_rope(
    const u16* __restrict__ xb,
    const u16* __restrict__ wqb, const u16* __restrict__ wkb,
    const u16* __restrict__ wvb,
    const float* __restrict__ cosT, const float* __restrict__ sinT,
    u16* __restrict__ qo, u16* __restrict__ ko, u16* __restrict__ vo) {
  __shared__ __align__(16) u16 a_lds[64 * 128];
  __shared__ __align__(16) u16 b_lds[64 * 128];
  const int tid = threadIdx.x;
  const int mt = blockIdx.x;            // 0..63
  const int by = blockIdx.y;            // 0..95
  const int mat = by >> 5;              // 0:q 1:k 2:v
  const int nt  = by & 31;
  const u16* w = (mat == 0) ? wqb : ((mat == 1) ? wkb : wvb);
  const int m0 = mt * 64, n0 = nt * 64;

#pragma unroll
  for (int i = 0; i < 4; ++i) {
    int idx = tid + i * 256;            // 0..1023
    int row = idx >> 4, e0 = (idx & 15) * 8;
    int hw = ((row << 7) | e0) ^ ((row & 7) << 3);
    bf8_t xa = *reinterpret_cast<const bf8_t*>(xb + (size_t)(m0 + row) * 128 + e0);
    *reinterpret_cast<bf8_t*>(&a_lds[hw]) = xa;
    bf8_t wa = *reinterpret_cast<const bf8_t*>(w + (size_t)(n0 + row) * 128 + e0);
    *reinterpret_cast<bf8_t*>(&b_lds[hw]) = wa;
  }
  __syncthreads();

  const int lane = tid & 63, wid = tid >> 6;
  const int wr = wid >> 1, wc = wid & 1;
  const int g = lane >> 4, c16 = lane & 15;
  f4_t acc[2][2];
#pragma unroll
  for (int a = 0; a < 2; ++a)
#pragma unroll
    for (int b = 0; b < 2; ++b) acc[a][b] = (f4_t)0.0f;

#pragma unroll
  for (int kc = 0; kc < 4; ++kc) {
    bf8_t af[2], bf_[2];
#pragma unroll
    for (int fr = 0; fr < 2; ++fr) {
      int row = wr * 32 + fr * 16 + c16;
      int hw = ((row << 7) | (kc * 32 + g * 8)) ^ ((row & 7) << 3);
      af[fr] = *reinterpret_cast<const bf8_t*>(&a_lds[hw]);
    }
#pragma unroll
    for (int fc = 0; fc < 2; ++fc) {
      int row = wc * 32 + fc * 16 + c16;
      int hw = ((row << 7) | (kc * 32 + g * 8)) ^ ((row & 7) << 3);
      bf_[fc] = *reinterpret_cast<const bf8_t*>(&b_lds[hw]);
    }
#pragma unroll
    for (int fr = 0; fr < 2; ++fr)
#pragma unroll
      for (int fc = 0; fc < 2; ++fc)
        acc[fr][fc] = __builtin_amdgcn_mfma_f32_16x16x32_bf16(af[fr], bf_[fc], acc[fr][fc], 0, 0, 0);
  }

  if (mat == 2) {
    // ---- V: transpose via LDS (stride 72), write vT_g[bh][dv][s] coalesced
    __syncthreads();                      // a_lds reads complete
#pragma unroll
    for (int fr = 0; fr < 2; ++fr)
#pragma unroll
      for (int fc = 0; fc < 2; ++fc)
#pragma unroll
        for (int j = 0; j < 4; ++j) {
          int fcol = wc * 32 + fc * 16 + c16;     // 0..63 (local dv)
          int m = wr * 32 + fr * 16 + g * 4 + j;  // 0..63 (local s)
          a_lds[fcol * 72 + m] = f2bf(acc[fr][fc][j]);
        }
    __syncthreads();
    const int b = mt >> 4, sl0 = m0 & 1023;
    const int hq = nt >> 1, dvb = (nt & 1) * 64;
#pragma unroll
    for (int i = 0; i < 2; ++i) {
      int r = tid >> 2, c0 = ((tid & 3) * 2 + i) * 8;   // r 0..63, c0 0..56
      bf8_t v = *reinterpret_cast<const bf8_t*>(&a_lds[r * 72 + c0]);
      size_t adr = ((size_t)((b * 16 + hq) * 128 + dvb + r)) * 1024 + sl0 + c0;
      *reinterpret_cast<bf8_t*>(vo + adr) = v;
    }
    return;
  }

  // ---- q/k: RoPE epilogue ----
  u16* outp = (mat == 0) ? qo : ko;
#pragma unroll
  for (int fr = 0; fr < 2; ++fr) {
#pragma unroll
    for (int fc = 0; fc < 2; ++fc) {
      int fcol = n0 + wc * 32 + fc * 16 + c16;   // 0..2047
      int h = fcol >> 7, d = fcol & 127, p = d >> 1;
#pragma unroll
      for (int j = 0; j < 4; ++j) {
        int m = m0 + wr * 32 + fr * 16 + g * 4 + j;
        int b = m >> 10, sl = m & 1023;
        float v = acc[fr][fc][j];
        float vx = __shfl_xor(v, 1);
        float cv = cosT[sl * 64 + p], sv = sinT[sl * 64 + p];
        if (!(lane & 1)) {
          float e_out = v * cv - vx * sv;
          float o_out = v * sv + vx * cv;
          u32 u = (u32)f2bf(e_out) | ((u32)f2bf(o_out) << 16);
          u32 elem = ((u32)((b * 16 + h) * 1024 + sl)) * 128 + (u32)d;
          reinterpret_cast<u32*>(outp)[elem >> 1] = u;
        }
      }
    }
  }
}

// ---------------- kernel B: flash attention, 32x32 MFMA, in-reg softmax ----
// 2-wave blocks (wave = 32 q-rows). Swapped QK^T (S^T = K*Q^T) makes each
// P-row lane-local (split across lane/lane+32); PV A-frags built in-register
// via cvt_pk + shfl_xor(32) (T12). No p_lds; l = exact f32 row sum.
__device__ __forceinline__ void stage_kv32(const u16* __restrict__ Kp,
                                           const u16* __restrict__ Vt, int t,
                                           int tid, u16* k_lds, u16* vT) {
#pragma unroll
  for (int i = 0; i < 8; ++i) {
    int ck = i * 128 + tid;                 // K chunk 0..1023 (contiguous 16B)
    int n = ck >> 4, c = (ck & 15) * 8;
    bf8_t kv = *reinterpret_cast<const bf8_t*>(Kp + (size_t)(t * 64 + n) * 128 + c);
    *reinterpret_cast<bf8_t*>(&k_lds[((n << 7) | c) ^ ((n & 7) << 3)]) = kv;
    int dv = ck >> 3, cc = (ck & 7) * 8;    // V chunk: row dv, 8 u16
    bf8_t vv = *reinterpret_cast<const bf8_t*>(Vt + (size_t)dv * 1024 + t * 64 + cc);
    *reinterpret_cast<bf8_t*>(&vT[dv * 72 + cc]) = vv;
  }
}

__global__ __launch_bounds__(128, 2) void attn(
    const u16* __restrict__ qw, const u16* __restrict__ kw,
    const u16* __restrict__ vtg, u16* __restrict__ yw) {
  __shared__ __align__(16) u16 k_lds[64 * 128];   // 16 KB, XOR swizzle
  __shared__ __align__(16) u16 vT[128 * 72];      // 18 KB, stride-72 pad
  const int tid = threadIdx.x, lane = tid & 63, wid = tid >> 6;
  const int q32 = lane & 31, hi = lane >> 5;
  const int bid = blockIdx.x;                 // 0..1023
  const int b6 = bid & 63, s6 = (bid >> 6) & 3, rnd = bid >> 8;
  const int bh = (b6 & 7) * 8 + (b6 >> 3);    // all of a bh's blocks on 1 XCD
  // flat balance: per CU-slot the 4 rounds contribute T sums 13+12+5+4 = 34
  int qt;
  if      (rnd == 0) qt = 12 + s6;
  else if (rnd == 1) qt = 11 - s6;
  else if (rnd == 2) qt = 4 + s6;
  else               qt = 3 - s6;
  const int T = qt + 1;
  const int b = bh >> 4, h = bh & 15;
  const u16* Qp = qw + (size_t)bh * SEQ * DH;
  const u16* Kp = kw + (size_t)bh * SEQ * DH;
  const u16* Vt = vtg + (size_t)bh * DH * SEQ;
  const float kscale = 0.08838834764831845f * 1.4426950408889634f; // rsqrt(128)*log2e
  const int qrow0 = qt * 64 + wid * 32;       // wave's 32 q-rows

  bf8_t qf[8];                                // Q as B-operand (col = q32)
#pragma unroll
  for (int kc = 0; kc < 8; ++kc)
    qf[kc] = *reinterpret_cast<const bf8_t*>(Qp + (size_t)(qrow0 + q32) * 128 + kc * 16 + hi * 8);

  f16v y0 = (f16v)0.0f, y1 = (f16v)0.0f, y2 = (f16v)0.0f, y3 = (f16v)0.0f;
  float m_run = -3e38f, l_run = 0.0f;

  stage_kv32(Kp, Vt, 0, tid, k_lds, vT);
  __syncthreads();

  for (int t = 0; t < T; ++t) {
    // ---- S^T = K * Q^T : sf0 = k-rows 0..31, sf1 = 32..63 (cols = q) ----
    f16v sf0 = (f16v)0.0f, sf1 = (f16v)0.0f;
    __builtin_amdgcn_s_setprio(1);
#pragma unroll
    for (int kc = 0; kc < 8; ++kc) {
      int c = kc * 16 + hi * 8;
      bf8_t k0 = *reinterpret_cast<const bf8_t*>(&k_lds[((q32 << 7) | c) ^ ((q32 & 7) << 3)]);
      bf8_t k1 = *reinterpret_cast<const bf8_t*>(&k_lds[(((32 + q32) << 7) | c) ^ ((q32 & 7) << 3)]);
      sf0 = __builtin_amdgcn_mfma_f32_32x32x16_bf16(k0, qf[kc], sf0, 0, 0, 0);
      sf1 = __builtin_amdgcn_mfma_f32_32x32x16_bf16(k1, qf[kc], sf1, 0, 0, 0);
    }
    __builtin_amdgcn_s_setprio(0);

    // ---- diagonal mask (last tile only); k-row = crow(r,hi), q-col = q32 ----
    if (t == T - 1) {
      int ql = wid * 32 + q32;
#pragma unroll
      for (int r = 0; r < 16; ++r) {
        int kl = (r & 3) + 8 * (r >> 2) + 4 * hi;
        if (kl > ql) sf0[r] = -3e38f;
        if (kl + 32 > ql) sf1[r] = -3e38f;
      }
    }

    // ---- row max (lane-local + 1 swap); defer-max rescale (rare) ----
    float mx = sf0[0];
#pragma unroll
    for (int r = 1; r < 16; ++r) mx = fmaxf(mx, sf0[r]);
#pragma unroll
    for (int r = 0; r < 16; ++r) mx = fmaxf(mx, sf1[r]);
    mx = fmaxf(mx, __shfl_xor(mx, 32));
    if (__any(mx > m_run + 8.0f)) {
      float mn = fmaxf(m_run, mx);
      float al = exp2f((m_run - mn) * kscale);
      m_run = mn;
      l_run *= al;
#pragma unroll
      for (int r = 0; r < 16; ++r) {
        int qp = (r & 3) + 8 * (r >> 2) + 4 * hi;     // yacc row's q-index
        float alr = __shfl(al, qp + (lane & 32));
        y0[r] *= alr; y1[r] *= alr; y2[r] *= alr; y3[r] *= alr;
      }
    }

    // ---- P = exp2((S - m)*ks); exact f32 row-sum for l ----
    float pv0[16], pv1[16];
#pragma unroll
    for (int r = 0; r < 16; ++r) {
      pv0[r] = exp2f((sf0[r] - m_run) * kscale);
      pv1[r] = exp2f((sf1[r] - m_run) * kscale);
    }
    float a0 = 0, a1 = 0, a2 = 0, a3 = 0;
#pragma unroll
    for (int r = 0; r < 16; r += 4) {
      a0 += pv0[r] + pv1[r];         a1 += pv0[r + 1] + pv1[r + 1];
      a2 += pv0[r + 2] + pv1[r + 2]; a3 += pv0[r + 3] + pv1[r + 3];
    }
    float sm = (a0 + a1) + (a2 + a3);
    sm += __shfl_xor(sm, 32);
    l_run += sm;

    // ---- T12: pack to bf16 pairs, exchange halves, build PV A-frags ----
    u32 W0[8], W1[8];
#pragma unroll
    for (int j = 0; j < 8; ++j) {
      W0[j] = cvtpk(pv0[2 * j], pv0[2 * j + 1]);
      W1[j] = cvtpk(pv1[2 * j], pv1[2 * j + 1]);
    }
    u32 sA0 = hi ? W0[0] : W0[2], sA1 = hi ? W0[1] : W0[3];
    u32 sA2 = hi ? W0[4] : W0[6], sA3 = hi ? W0[5] : W0[7];
    u32 sB0 = hi ? W1[0] : W1[2], sB1 = hi ? W1[1] : W1[3];
    u32 sB2 = hi ? W1[4] : W1[6], sB3 = hi ? W1[5] : W1[7];
    u32 rA0 = (u32)__shfl_xor((int)sA0, 32), rA1 = (u32)__shfl_xor((int)sA1, 32);
    u32 rA2 = (u32)__shfl_xor((int)sA2, 32), rA3 = (u32)__shfl_xor((int)sA3, 32);
    u32 rB0 = (u32)__shfl_xor((int)sB0, 32), rB1 = (u32)__shfl_xor((int)sB1, 32);
    u32 rB2 = (u32)__shfl_xor((int)sB2, 32), rB3 = (u32)__shfl_xor((int)sB3, 32);
    bf8_t pa0 = mk8(hi ? rA0 : W0[0], hi ? rA1 : W0[1], hi ? W0[2] : rA0, hi ? W0[3] : rA1);
    bf8_t pa1 = mk8(hi ? rA2 : W0[4], hi ? rA3 : W0[5], hi ? W0[6] : rA2, hi ? W0[7] : rA3);
    bf8_t pa2 = mk8(hi ? rB0 : W1[0], hi ? rB1 : W1[1], hi ? W1[2] : rB0, hi ? W1[3] : rB1);
    bf8_t pa3 = mk8(hi ? rB2 : W1[4], hi ? rB3 : W1[5], hi ? W1[6] : rB2, hi ? W1[7] : rB3);

    // ---- y += P V  (B = vT rows, col = dv = dvb*32 + q32) ----
    __builtin_amdgcn_s_setprio(1);
#define PVDV(YY, DVB)                                                          \
    { int vb = ((DVB) * 32 + q32) * 72 + hi * 8;                               \
      bf8_t v0 = *reinterpret_cast<const bf8_t*>(&vT[vb]);                     \
      bf8_t v1 = *reinterpret_cast<const bf8_t*>(&vT[vb + 16]);                \
      bf8_t v2 = *reinterpret_cast<const bf8_t*>(&vT[vb + 32]);                \
      bf8_t v3 = *reinterpret_cast<const bf8_t*>(&vT[vb + 48]);                \
      YY = __builtin_amdgcn_mfma_f32_32x32x16_bf16(pa0, v0, YY, 0, 0, 0);      \
      YY = __builtin_amdgcn_mfma_f32_32x32x16_bf16(pa1, v1, YY, 0, 0, 0);      \
      YY = __builtin_amdgcn_mfma_f32_32x32x16_bf16(pa2, v2, YY, 0, 0, 0);      \
      YY = __builtin_amdgcn_mfma_f32_32x32x16_bf16(pa3, v3, YY, 0, 0, 0); }
    PVDV(y0, 0) PVDV(y1, 1) PVDV(y2, 2) PVDV(y3, 3)
#undef PVDV
    __builtin_amdgcn_s_setprio(0);

    __syncthreads();
    if (t + 1 < T) {
      stage_kv32(Kp, Vt, t + 1, tid, k_lds, vT);
      __syncthreads();
    }
  }

  // ---- epilogue: y /= l (l lives in lane q32); store bf16 ----
  float rl = 1.0f / l_run;
#pragma unroll
  for (int r = 0; r < 16; ++r) {
    int qp = (r & 3) + 8 * (r >> 2) + 4 * hi;
    float rlr = __shfl(rl, qp + (lane & 32));
    size_t base = ((size_t)(b * 1024 + qrow0 + qp)) * 2048 + h * 128 + q32;
    yw[base]      = f2bf(y0[r] * rlr);
    yw[base + 32] = f2bf(y1[r] * rlr);
    yw[base + 64] = f2bf(y2[r] * rlr);
    yw[base + 96] = f2bf(y3[r] * rlr);
  }
}

// ---------------- kernel C: output projection (split-K=2, atomic) ----------
__global__ __launch_bounds__(256) void oproj(
    const u16* __restrict__ yw, const u16* __restrict__ wob,
    float* __restrict__ out) {
  __shared__ __align__(16) u16 a_lds[64 * 64];
  __shared__ __align__(16) u16 b_lds[64 * 64];
  const int tid = threadIdx.x, lane = tid & 63, wid = tid >> 6;
  const int g = lane >> 4, c16 = lane & 15;
  const int wr = wid >> 1, wc = wid & 1;
  const int m0 = blockIdx.x * 64, n0 = blockIdx.y * 64;
  const int z = blockIdx.z;
  f4_t acc[2][2];
#pragma unroll
  for (int a = 0; a < 2; ++a)
#pragma unroll
    for (int b = 0; b < 2; ++b) acc[a][b] = (f4_t)0.0f;

  for (int kt = z * 16; kt < z * 16 + 16; ++kt) {
    int kb = kt * 64;
#pragma unroll
    for (int i = 0; i < 2; ++i) {
      int idx = tid + i * 256;            // 0..511
      int row = idx >> 3, k0 = (idx & 7) * 8;
      int hw = ((row << 6) | k0) ^ ((row & 7) << 3);
      bf8_t av = *reinterpret_cast<const bf8_t*>(yw + (size_t)(m0 + row) * 2048 + kb + k0);
      *reinterpret_cast<bf8_t*>(&a_lds[hw]) = av;
      bf8_t bv = *reinterpret_cast<const bf8_t*>(wob + (size_t)(n0 + row) * 2048 + kb + k0);
      *reinterpret_cast<bf8_t*>(&b_lds[hw]) = bv;
    }
    __syncthreads();
#pragma unroll
    for (int c = 0; c < 2; ++c) {
      bf8_t af[2], bf_[2];
#pragma unroll
      for (int fr = 0; fr < 2; ++fr) {
        int row = wr * 32 + fr * 16 + c16;
        int hw = ((row << 6) | (c * 32 + g * 8)) ^ ((row & 7) << 3);
        af[fr] = *reinterpret_cast<const bf8_t*>(&a_lds[hw]);
      }
#pragma unroll
      for (int fc = 0; fc < 2; ++fc) {
        int row = wc * 32 + fc * 16 + c16;
        int hw = ((row << 6) | (c * 32 + g * 8)) ^ ((row & 7) << 3);
        bf_[fc] = *reinterpret_cast<const bf8_t*>(&b_lds[hw]);
      }
#pragma unroll
      for (int fr = 0; fr < 2; ++fr)
#pragma unroll
        for (int fc = 0; fc < 2; ++fc)
          acc[fr][fc] = __builtin_amdgcn_mfma_f32_16x16x32_bf16(af[fr], bf_[fc], acc[fr][fc], 0, 0, 0);
    }
    __syncthreads();
  }
#pragma unroll
  for (int fr = 0; fr < 2; ++fr)
#pragma unroll
    for (int fc = 0; fc < 2; ++fc)
#pragma unroll
      for (int j = 0; j < 4; ++j) {
        int m = m0 + wr * 32 + fr * 16 + g * 4 + j;
        int e = n0 + wc * 32 + fc * 16 + c16;
        atomicAdd(&out[(size_t)m * 128 + e], acc[fr][fc][j]);  // 2 addends: exact
      }
}

// ---------------------------------------------------------------------------
extern "C" void kernel_launch(void* const* d_in, const int* in_sizes, int n_in,
                              void* d_out, int out_size, void* d_ws, size_t ws_size,
                              hipStream_t stream) {
  const float* x  = (const float*)d_in[0];
  const float* wq = (const float*)d_in[1];
  const float* wk = (const float*)d_in[2];
  const float* wv = (const float*)d_in[3];
  const float* wo = (const float*)d_in[4];
  float* out = (float*)d_out;

  char* ws = (char*)d_ws;
  const size_t NEED = (512ull << 10) + 4ull * (16ull << 20) + (3ull << 20);
  if (ws_size < NEED) return;
  float* cosT = (float*)ws;
  float* sinT = cosT + 64 * 1024;
  u16* qws = (u16*)(ws + (512 << 10));
  u16* kws = qws + (8u << 20);
  u16* vws = kws + (8u << 20);      // vT_g[bh][dv][s]
  u16* yws = vws + (8u << 20);
  u16* xb  = yws + (8u << 20);
  u16* wqb = xb  + (1u << 19);
  u16* wkb = wqb + (1u << 18);
  u16* wvb = wkb + (1u << 18);
  u16* wob = wvb + (1u << 18);

  hipMemsetAsync(d_out, 0, (size_t)out_size * sizeof(float), stream);
  to_bf16<<<768, 256, 0, stream>>>(x, wq, wk, wv, wo, xb, wqb, wkb, wvb, wob);
  rope_tables<<<256, 256, 0, stream>>>(cosT, sinT);
  qkv_rope<<<dim3(64, 96), 256, 0, stream>>>(xb, wqb, wkb, wvb, cosT, sinT, qws, kws, vws);
  attn<<<1024, 128, 0, stream>>>(qws, kws, vws, yws);
  oproj<<<dim3(64, 2, 2), 256, 0, stream>>>(yws, wob, out);
}

// Round 8
// 113.084 us; speedup vs baseline: 1.3668x; 1.3668x over previous
//
#include <hip/hip_runtime.h>

typedef unsigned short u16;
typedef unsigned int   u32;
typedef __attribute__((ext_vector_type(8))) short bf8_t;   // 8 bf16 (4 VGPR)
typedef __attribute__((ext_vector_type(4))) float f4_t;

#define SEQ   1024
#define NH    16
#define DH    128
#define BATCH 4
#define MROWS 4096      // BATCH*SEQ
#define FDIM  2048      // NH*DH

__device__ __forceinline__ u16 f2bf(float f) {
  union { float f; u32 u; } v; v.f = f;
  u32 u = v.u;
  u += 0x7fffu + ((u >> 16) & 1u);   // RNE
  return (u16)(u >> 16);
}

// ---------------- kernel P: fp32 -> bf16 pre-conversion --------------------
__global__ __launch_bounds__(256) void to_bf16(
    const float* __restrict__ x,  const float* __restrict__ wq,
    const float* __restrict__ wk, const float* __restrict__ wv,
    const float* __restrict__ wo,
    u16* __restrict__ xb, u16* __restrict__ wqb, u16* __restrict__ wkb,
    u16* __restrict__ wvb, u16* __restrict__ wob) {
  int i = blockIdx.x * 256 + threadIdx.x;   // 0..196607
  const float* s; u16* d; int o;
  if      (i <  65536) { s = x;  d = xb;  o = i; }
  else if (i <  98304) { s = wq; d = wqb; o = i - 65536; }
  else if (i < 131072) { s = wk; d = wkb; o = i - 98304; }
  else if (i < 163840) { s = wv; d = wvb; o = i - 131072; }
  else                 { s = wo; d = wob; o = i - 163840; }
  const f4_t* sp = reinterpret_cast<const f4_t*>(s + (size_t)o * 8);
  f4_t a = sp[0], b = sp[1];
  bf8_t pk;
#pragma unroll
  for (int j = 0; j < 4; ++j) { pk[j] = (short)f2bf(a[j]); pk[4 + j] = (short)f2bf(b[j]); }
  *reinterpret_cast<bf8_t*>(d + (size_t)o * 8) = pk;
}

// ---------------- kernel 0: RoPE tables ------------------------------------
__global__ __launch_bounds__(256) void rope_tables(float* __restrict__ cosT,
                                                   float* __restrict__ sinT) {
  int i = blockIdx.x * 256 + threadIdx.x;      // 65536 = 1024*64
  int s = i >> 6, p = i & 63;
  float ef = (float)(2 * p) / 128.0f;
  float angf = (float)pow(10000.0, (double)ef);
  float thf  = (float)s * angf;
  double th  = (double)thf;
  cosT[i] = (float)cos(th);
  sinT[i] = (float)sin(th);
}

// ---------------- kernel A: fused QKV projection + RoPE --------------------
// q,k: RoPE'd, [bh][s][d].  v: written TRANSPOSED to vT_g[bh][dv][s].
__global__ __launch_bounds__(256) void qkv_rope(
    const u16* __restrict__ xb,
    const u16* __restrict__ wqb, const u16* __restrict__ wkb,
    const u16* __restrict__ wvb,
    const float* __restrict__ cosT, const float* __restrict__ sinT,
    u16* __restrict__ qo, u16* __restrict__ ko, u16* __restrict__ vo) {
  __shared__ __align__(16) u16 a_lds[64 * 128];
  __shared__ __align__(16) u16 b_lds[64 * 128];
  const int tid = threadIdx.x;
  const int mt = blockIdx.x;            // 0..63
  const int by = blockIdx.y;            // 0..95
  const int mat = by >> 5;              // 0:q 1:k 2:v
  const int nt  = by & 31;
  const u16* w = (mat == 0) ? wqb : ((mat == 1) ? wkb : wvb);
  const int m0 = mt * 64, n0 = nt * 64;

#pragma unroll
  for (int i = 0; i < 4; ++i) {
    int idx = tid + i * 256;            // 0..1023
    int row = idx >> 4, e0 = (idx & 15) * 8;
    int hw = ((row << 7) | e0) ^ ((row & 7) << 3);
    bf8_t xa = *reinterpret_cast<const bf8_t*>(xb + (size_t)(m0 + row) * 128 + e0);
    *reinterpret_cast<bf8_t*>(&a_lds[hw]) = xa;
    bf8_t wa = *reinterpret_cast<const bf8_t*>(w + (size_t)(n0 + row) * 128 + e0);
    *reinterpret_cast<bf8_t*>(&b_lds[hw]) = wa;
  }
  __syncthreads();

  const int lane = tid & 63, wid = tid >> 6;
  const int wr = wid >> 1, wc = wid & 1;
  const int g = lane >> 4, c16 = lane & 15;
  f4_t acc[2][2];
#pragma unroll
  for (int a = 0; a < 2; ++a)
#pragma unroll
    for (int b = 0; b < 2; ++b) acc[a][b] = (f4_t)0.0f;

#pragma unroll
  for (int kc = 0; kc < 4; ++kc) {
    bf8_t af[2], bf_[2];
#pragma unroll
    for (int fr = 0; fr < 2; ++fr) {
      int row = wr * 32 + fr * 16 + c16;
      int hw = ((row << 7) | (kc * 32 + g * 8)) ^ ((row & 7) << 3);
      af[fr] = *reinterpret_cast<const bf8_t*>(&a_lds[hw]);
    }
#pragma unroll
    for (int fc = 0; fc < 2; ++fc) {
      int row = wc * 32 + fc * 16 + c16;
      int hw = ((row << 7) | (kc * 32 + g * 8)) ^ ((row & 7) << 3);
      bf_[fc] = *reinterpret_cast<const bf8_t*>(&b_lds[hw]);
    }
#pragma unroll
    for (int fr = 0; fr < 2; ++fr)
#pragma unroll
      for (int fc = 0; fc < 2; ++fc)
        acc[fr][fc] = __builtin_amdgcn_mfma_f32_16x16x32_bf16(af[fr], bf_[fc], acc[fr][fc], 0, 0, 0);
  }

  if (mat == 2) {
    // ---- V: transpose via LDS (stride 72), write vT_g[bh][dv][s] coalesced
    __syncthreads();                      // a_lds reads complete
#pragma unroll
    for (int fr = 0; fr < 2; ++fr)
#pragma unroll
      for (int fc = 0; fc < 2; ++fc)
#pragma unroll
        for (int j = 0; j < 4; ++j) {
          int fcol = wc * 32 + fc * 16 + c16;     // 0..63 (local dv)
          int m = wr * 32 + fr * 16 + g * 4 + j;  // 0..63 (local s)
          a_lds[fcol * 72 + m] = f2bf(acc[fr][fc][j]);
        }
    __syncthreads();
    const int b = mt >> 4, sl0 = m0 & 1023;
    const int hq = nt >> 1, dvb = (nt & 1) * 64;
#pragma unroll
    for (int i = 0; i < 2; ++i) {
      int r = tid >> 2, c0 = ((tid & 3) * 2 + i) * 8;   // r 0..63, c0 0..56
      bf8_t v = *reinterpret_cast<const bf8_t*>(&a_lds[r * 72 + c0]);
      size_t adr = ((size_t)((b * 16 + hq) * 128 + dvb + r)) * 1024 + sl0 + c0;
      *reinterpret_cast<bf8_t*>(vo + adr) = v;
    }
    return;
  }

  // ---- q/k: RoPE epilogue ----
  u16* outp = (mat == 0) ? qo : ko;
#pragma unroll
  for (int fr = 0; fr < 2; ++fr) {
#pragma unroll
    for (int fc = 0; fc < 2; ++fc) {
      int fcol = n0 + wc * 32 + fc * 16 + c16;   // 0..2047
      int h = fcol >> 7, d = fcol & 127, p = d >> 1;
#pragma unroll
      for (int j = 0; j < 4; ++j) {
        int m = m0 + wr * 32 + fr * 16 + g * 4 + j;
        int b = m >> 10, sl = m & 1023;
        float v = acc[fr][fc][j];
        float vx = __shfl_xor(v, 1);
        float cv = cosT[sl * 64 + p], sv = sinT[sl * 64 + p];
        if (!(lane & 1)) {
          float e_out = v * cv - vx * sv;
          float o_out = v * sv + vx * cv;
          u32 u = (u32)f2bf(e_out) | ((u32)f2bf(o_out) << 16);
          u32 elem = ((u32)((b * 16 + h) * 1024 + sl)) * 128 + (u32)d;
          reinterpret_cast<u32*>(outp)[elem >> 1] = u;
        }
      }
    }
  }
}

// ---------------- kernel B: flash attention (r5 datapath, 16 waves/CU) -----
// 4 waves x 16 q-rows; qt = 2pp + (wid>>1); T = pp+1 KV tiles of 64.
// LDS exactly 40 KB -> 4 blocks/CU, grid 1024 = fully resident, per-CU
// T-sum = 34 (flat balance). P path = round-5 proven (scalar swizzled p_lds).
__device__ __forceinline__ void stage_kv(const u16* __restrict__ Kp,
                                         const u16* __restrict__ Vt, int t,
                                         int tid, u16* k_lds, u16* vT) {
#pragma unroll
  for (int i = 0; i < 4; ++i) {
    int n = tid >> 2, c0 = ((tid & 3) * 4 + i) * 8;            // K: 64x128
    bf8_t kv = *reinterpret_cast<const bf8_t*>(Kp + (size_t)(t * 64 + n) * 128 + c0);
    *reinterpret_cast<bf8_t*>(&k_lds[(n << 7) | (c0 ^ ((n & 7) << 3))]) = kv;
    int dv = tid >> 1, c1 = ((tid & 1) * 4 + i) * 8;           // vT: 128x64
    bf8_t vv = *reinterpret_cast<const bf8_t*>(Vt + (size_t)dv * 1024 + t * 64 + c1);
    *reinterpret_cast<bf8_t*>(&vT[(dv << 6) | (c1 ^ ((dv & 7) << 3))]) = vv;
  }
}

__global__ __launch_bounds__(256, 4) void attn(
    const u16* __restrict__ qw, const u16* __restrict__ kw,
    const u16* __restrict__ vtg, u16* __restrict__ yw) {
  __shared__ __align__(16) u16 k_lds[64 * 128];       // 16 KB, XOR swizzle
  __shared__ __align__(16) u16 vT[128 * 64];          // 16 KB, XOR swizzle
  __shared__ __align__(16) u16 p_lds[4][16 * 64];     //  8 KB, per-wave [q][n]
  const int tid = threadIdx.x, lane = tid & 63, wid = tid >> 6;
  const int g = lane >> 4, c16 = lane & 15;
  const int bid = blockIdx.x;                  // 0..1023
  const int s6 = (bid >> 6) & 3, rnd = bid >> 8;
  int pp;                                      // per-CU T-sum = 34 (flat)
  if      (rnd == 0) pp = 15 - s6;
  else if (rnd == 1) pp = 8 + s6;
  else if (rnd == 2) pp = 7 - s6;
  else               pp = s6;
  const int bh = bid & 63;                     // blocks of a bh share XCD
  const int b = bh >> 4, h = bh & 15;
  const int qt = 2 * pp + (wid >> 1);          // 32-row q-tile index
  const int T = pp + 1;
  const u16* Qp = qw + (size_t)bh * SEQ * DH;
  const u16* Kp = kw + (size_t)bh * SEQ * DH;
  const u16* Vt = vtg + (size_t)bh * DH * SEQ;
  const float kscale = 0.08838834764831845f * 1.4426950408889634f; // rsqrt(128)*log2e
  const int qrow0 = qt * 32 + (wid & 1) * 16;  // wave's 16 q-rows (global)
  const int moff = (wid >> 1) * 32 + (wid & 1) * 16;  // diag-mask offset

  bf8_t qf[4];
#pragma unroll
  for (int c = 0; c < 4; ++c)
    qf[c] = *reinterpret_cast<const bf8_t*>(Qp + (size_t)(qrow0 + c16) * 128 + c * 32 + g * 8);

  f4_t yacc[8];
#pragma unroll
  for (int f = 0; f < 8; ++f) yacc[f] = (f4_t)0.0f;
  float m_run[4], l_run[4];
#pragma unroll
  for (int j = 0; j < 4; ++j) { m_run[j] = -3e38f; l_run[j] = 0.0f; }

  stage_kv(Kp, Vt, 0, tid, k_lds, vT);
  __syncthreads();

  for (int t = 0; t < T; ++t) {
    // ---- S = Q K^T ----
    f4_t sf[4];
#pragma unroll
    for (int nf = 0; nf < 4; ++nf) sf[nf] = (f4_t)0.0f;
    __builtin_amdgcn_s_setprio(1);
#pragma unroll
    for (int nf = 0; nf < 4; ++nf) {
      int row = nf * 16 + c16;
#pragma unroll
      for (int kc = 0; kc < 4; ++kc) {
        int hw = (row << 7) | ((kc * 32 + g * 8) ^ ((row & 7) << 3));
        bf8_t kf = *reinterpret_cast<const bf8_t*>(&k_lds[hw]);
        sf[nf] = __builtin_amdgcn_mfma_f32_16x16x32_bf16(qf[kc], kf, sf[nf], 0, 0, 0);
      }
    }
    __builtin_amdgcn_s_setprio(0);

    // ---- diagonal mask (last tile only) ----
    if (t == T - 1) {
#pragma unroll
      for (int nf = 0; nf < 4; ++nf) {
        int keyc = nf * 16 + c16;
#pragma unroll
        for (int j = 0; j < 4; ++j)
          if (keyc > moff + g * 4 + j) sf[nf][j] = -3e38f;
      }
    }

    // ---- defer-max guard: cross-lane reduce only when needed ----
    int chk = 0;
#pragma unroll
    for (int j = 0; j < 4; ++j) {
      float lmx = fmaxf(fmaxf(sf[0][j], sf[1][j]), fmaxf(sf[2][j], sf[3][j]));
      chk |= (lmx > m_run[j] + 32.0f) ? 1 : 0;
    }
    if (__any(chk)) {
      float lm[4];
#pragma unroll
      for (int j = 0; j < 4; ++j) {
        lm[j] = fmaxf(fmaxf(sf[0][j], sf[1][j]), fmaxf(sf[2][j], sf[3][j]));
        lm[j] = fmaxf(lm[j], __shfl_xor(lm[j], 1));
        lm[j] = fmaxf(lm[j], __shfl_xor(lm[j], 2));
        lm[j] = fmaxf(lm[j], __shfl_xor(lm[j], 4));
        lm[j] = fmaxf(lm[j], __shfl_xor(lm[j], 8));
      }
#pragma unroll
      for (int j = 0; j < 4; ++j) {
        float mn = fmaxf(m_run[j], lm[j]);
        float alpha = exp2f((m_run[j] - mn) * kscale);
        m_run[j] = mn;
        l_run[j] *= alpha;
#pragma unroll
        for (int f = 0; f < 8; ++f) yacc[f][j] *= alpha;
      }
    }

    // ---- P = exp2((S-m)*ks); f32 row-sum; bf16 -> swizzled p_lds ----
    float rs[4];
#pragma unroll
    for (int j = 0; j < 4; ++j) rs[j] = 0.0f;
#pragma unroll
    for (int nf = 0; nf < 4; ++nf) {
#pragma unroll
      for (int j = 0; j < 4; ++j) {
        float pv = exp2f((sf[nf][j] - m_run[j]) * kscale);
        rs[j] += pv;
        int q = g * 4 + j, n = nf * 16 + c16;
        int hw = ((q << 6) | n) ^ ((q & 7) << 3);
        p_lds[wid][hw] = f2bf(pv);
      }
    }
#pragma unroll
    for (int j = 0; j < 4; ++j) {
      rs[j] += __shfl_xor(rs[j], 1);
      rs[j] += __shfl_xor(rs[j], 2);
      rs[j] += __shfl_xor(rs[j], 4);
      rs[j] += __shfl_xor(rs[j], 8);
      l_run[j] += rs[j];
    }

    // ---- PV A-frags (wave-private p_lds; DS in-order per wave) ----
    bf8_t pa[2];
#pragma unroll
    for (int cc = 0; cc < 2; ++cc) {
      int hw = ((c16 << 6) | (cc * 32 + g * 8)) ^ ((c16 & 7) << 3);
      pa[cc] = *reinterpret_cast<const bf8_t*>(&p_lds[wid][hw]);
    }

    // ---- y += P V ----
    __builtin_amdgcn_s_setprio(1);
#pragma unroll
    for (int f = 0; f < 8; ++f) {
      int row = f * 16 + c16;
      int sw = (row & 7) << 3;
      bf8_t v0 = *reinterpret_cast<const bf8_t*>(&vT[(row << 6) | ((g * 8) ^ sw)]);
      bf8_t v1 = *reinterpret_cast<const bf8_t*>(&vT[(row << 6) | ((32 + g * 8) ^ sw)]);
      yacc[f] = __builtin_amdgcn_mfma_f32_16x16x32_bf16(pa[0], v0, yacc[f], 0, 0, 0);
      yacc[f] = __builtin_amdgcn_mfma_f32_16x16x32_bf16(pa[1], v1, yacc[f], 0, 0, 0);
    }
    __builtin_amdgcn_s_setprio(0);

    __syncthreads();                     // everyone done reading k/vT
    if (t + 1 < T) {
      stage_kv(Kp, Vt, t + 1, tid, k_lds, vT);
      __syncthreads();
    }
  }

  // ---- epilogue: y /= l; store bf16 pairs ----
  float rl[4];
#pragma unroll
  for (int j = 0; j < 4; ++j) rl[j] = 1.0f / l_run[j];
#pragma unroll
  for (int f = 0; f < 8; ++f) {
#pragma unroll
    for (int j = 0; j < 4; ++j) {
      float yv = yacc[f][j] * rl[j];
      float yn = __shfl_xor(yv, 1);
      if (!(lane & 1)) {
        int s_ = qrow0 + g * 4 + j;
        int dv = f * 16 + c16;
        u32 u = (u32)f2bf(yv) | ((u32)f2bf(yn) << 16);
        u32 elem = ((u32)(b * 1024 + s_)) * 2048 + (u32)(h * 128 + dv);
        reinterpret_cast<u32*>(yw)[elem >> 1] = u;
      }
    }
  }
}

// ---------------- kernel C: output projection (split-K=2, atomic) ----------
__global__ __launch_bounds__(256) void oproj(
    const u16* __restrict__ yw, const u16* __restrict__ wob,
    float* __restrict__ out) {
  __shared__ __align__(16) u16 a_lds[64 * 64];
  __shared__ __align__(16) u16 b_lds[64 * 64];
  const int tid = threadIdx.x, lane = tid & 63, wid = tid >> 6;
  const int g = lane >> 4, c16 = lane & 15;
  const int wr = wid >> 1, wc = wid & 1;
  const int m0 = blockIdx.x * 64, n0 = blockIdx.y * 64;
  const int z = blockIdx.z;
  f4_t acc[2][2];
#pragma unroll
  for (int a = 0; a < 2; ++a)
#pragma unroll
    for (int b = 0; b < 2; ++b) acc[a][b] = (f4_t)0.0f;

  for (int kt = z * 16; kt < z * 16 + 16; ++kt) {
    int kb = kt * 64;
#pragma unroll
    for (int i = 0; i < 2; ++i) {
      int idx = tid + i * 256;            // 0..511
      int row = idx >> 3, k0 = (idx & 7) * 8;
      int hw = ((row << 6) | k0) ^ ((row & 7) << 3);
      bf8_t av = *reinterpret_cast<const bf8_t*>(yw + (size_t)(m0 + row) * 2048 + kb + k0);
      *reinterpret_cast<bf8_t*>(&a_lds[hw]) = av;
      bf8_t bv = *reinterpret_cast<const bf8_t*>(wob + (size_t)(n0 + row) * 2048 + kb + k0);
      *reinterpret_cast<bf8_t*>(&b_lds[hw]) = bv;
    }
    __syncthreads();
#pragma unroll
    for (int c = 0; c < 2; ++c) {
      bf8_t af[2], bf_[2];
#pragma unroll
      for (int fr = 0; fr < 2; ++fr) {
        int row = wr * 32 + fr * 16 + c16;
        int hw = ((row << 6) | (c * 32 + g * 8)) ^ ((row & 7) << 3);
        af[fr] = *reinterpret_cast<const bf8_t*>(&a_lds[hw]);
      }
#pragma unroll
      for (int fc = 0; fc < 2; ++fc) {
        int row = wc * 32 + fc * 16 + c16;
        int hw = ((row << 6) | (c * 32 + g * 8)) ^ ((row & 7) << 3);
        bf_[fc] = *reinterpret_cast<const bf8_t*>(&b_lds[hw]);
      }
#pragma unroll
      for (int fr = 0; fr < 2; ++fr)
#pragma unroll
        for (int fc = 0; fc < 2; ++fc)
          acc[fr][fc] = __builtin_amdgcn_mfma_f32_16x16x32_bf16(af[fr], bf_[fc], acc[fr][fc], 0, 0, 0);
    }
    __syncthreads();
  }
#pragma unroll
  for (int fr = 0; fr < 2; ++fr)
#pragma unroll
    for (int fc = 0; fc < 2; ++fc)
#pragma unroll
      for (int j = 0; j < 4; ++j) {
        int m = m0 + wr * 32 + fr * 16 + g * 4 + j;
        int e = n0 + wc * 32 + fc * 16 + c16;
        atomicAdd(&out[(size_t)m * 128 + e], acc[fr][fc][j]);  // 2 addends: exact
      }
}

// ---------------------------------------------------------------------------
extern "C" void kernel_launch(void* const* d_in, const int* in_sizes, int n_in,
                              void* d_out, int out_size, void* d_ws, size_t ws_size,
                              hipStream_t stream) {
  const float* x  = (const float*)d_in[0];
  const float* wq = (const float*)d_in[1];
  const float* wk = (const float*)d_in[2];
  const float* wv = (const float*)d_in[3];
  const float* wo = (const float*)d_in[4];
  float* out = (float*)d_out;

  char* ws = (char*)d_ws;
  const size_t NEED = (512ull << 10) + 4ull * (16ull << 20) + (3ull << 20);
  if (ws_size < NEED) return;
  float* cosT = (float*)ws;
  float* sinT = cosT + 64 * 1024;
  u16* qws = (u16*)(ws + (512 << 10));
  u16* kws = qws + (8u << 20);
  u16* vws = kws + (8u << 20);      // vT_g[bh][dv][s]
  u16* yws = vws + (8u << 20);
  u16* xb  = yws + (8u << 20);
  u16* wqb = xb  + (1u << 19);
  u16* wkb = wqb + (1u << 18);
  u16* wvb = wkb + (1u << 18);
  u16* wob = wvb + (1u << 18);

  hipMemsetAsync(d_out, 0, (size_t)out_size * sizeof(float), stream);
  to_bf16<<<768, 256, 0, stream>>>(x, wq, wk, wv, wo, xb, wqb, wkb, wvb, wob);
  rope_tables<<<256, 256, 0, stream>>>(cosT, sinT);
  qkv_rope<<<dim3(64, 96), 256, 0, stream>>>(xb, wqb, wkb, wvb, cosT, sinT, qws, kws, vws);
  attn<<<1024, 256, 0, stream>>>(qws, kws, vws, yws);
  oproj<<<dim3(64, 2, 2), 256, 0, stream>>>(yws, wob, out);
}

// Round 9
// 99.161 us; speedup vs baseline: 1.5588x; 1.1404x over previous
//
#include <hip/hip_runtime.h>

typedef unsigned short u16;
typedef unsigned int   u32;
typedef __attribute__((ext_vector_type(8))) short bf8_t;   // 8 bf16 (4 VGPR)
typedef __attribute__((ext_vector_type(4))) float f4_t;

#define SEQ   1024
#define NH    16
#define DH    128
#define BATCH 4
#define MROWS 4096      // BATCH*SEQ
#define FDIM  2048      // NH*DH

__device__ __forceinline__ u16 f2bf(float f) {
  union { float f; u32 u; } v; v.f = f;
  u32 u = v.u;
  u += 0x7fffu + ((u >> 16) & 1u);   // RNE
  return (u16)(u >> 16);
}

// ---------------- kernel P: fp32 -> bf16 pre-conversion --------------------
__global__ __launch_bounds__(256) void to_bf16(
    const float* __restrict__ x,  const float* __restrict__ wq,
    const float* __restrict__ wk, const float* __restrict__ wv,
    const float* __restrict__ wo,
    u16* __restrict__ xb, u16* __restrict__ wqb, u16* __restrict__ wkb,
    u16* __restrict__ wvb, u16* __restrict__ wob) {
  int i = blockIdx.x * 256 + threadIdx.x;   // 0..196607
  const float* s; u16* d; int o;
  if      (i <  65536) { s = x;  d = xb;  o = i; }
  else if (i <  98304) { s = wq; d = wqb; o = i - 65536; }
  else if (i < 131072) { s = wk; d = wkb; o = i - 98304; }
  else if (i < 163840) { s = wv; d = wvb; o = i - 131072; }
  else                 { s = wo; d = wob; o = i - 163840; }
  const f4_t* sp = reinterpret_cast<const f4_t*>(s + (size_t)o * 8);
  f4_t a = sp[0], b = sp[1];
  bf8_t pk;
#pragma unroll
  for (int j = 0; j < 4; ++j) { pk[j] = (short)f2bf(a[j]); pk[4 + j] = (short)f2bf(b[j]); }
  *reinterpret_cast<bf8_t*>(d + (size_t)o * 8) = pk;
}

// ---------------- kernel 0: RoPE tables ------------------------------------
// angf: f64 pow rounded to f32 (bit-match np.power in f32); theta: f32 mul
// (exact match); sin/cos: f32 OCML (full range reduction) — no f64 transcend.
__global__ __launch_bounds__(256) void rope_tables(float* __restrict__ cosT,
                                                   float* __restrict__ sinT) {
  int i = blockIdx.x * 256 + threadIdx.x;      // 65536 = 1024*64
  int s = i >> 6, p = i & 63;
  float ef = (float)(2 * p) / 128.0f;
  float angf = (float)pow(10000.0, (double)ef);
  float thf  = (float)s * angf;
  cosT[i] = cosf(thf);
  sinT[i] = sinf(thf);
}

// ---------------- kernel A: fused QKV projection + RoPE --------------------
// q,k: RoPE'd, [bh][s][d].  v: written TRANSPOSED to vT_g[bh][dv][s].
__global__ __launch_bounds__(256) void qkv_rope(
    const u16* __restrict__ xb,
    const u16* __restrict__ wqb, const u16* __restrict__ wkb,
    const u16* __restrict__ wvb,
    const float* __restrict__ cosT, const float* __restrict__ sinT,
    u16* __restrict__ qo, u16* __restrict__ ko, u16* __restrict__ vo) {
  __shared__ __align__(16) u16 a_lds[64 * 128];
  __shared__ __align__(16) u16 b_lds[64 * 128];
  const int tid = threadIdx.x;
  const int mt = blockIdx.x;            // 0..63
  const int by = blockIdx.y;            // 0..95
  const int mat = by >> 5;              // 0:q 1:k 2:v
  const int nt  = by & 31;
  const u16* w = (mat == 0) ? wqb : ((mat == 1) ? wkb : wvb);
  const int m0 = mt * 64, n0 = nt * 64;

#pragma unroll
  for (int i = 0; i < 4; ++i) {
    int idx = tid + i * 256;            // 0..1023
    int row = idx >> 4, e0 = (idx & 15) * 8;
    int hw = ((row << 7) | e0) ^ ((row & 7) << 3);
    bf8_t xa = *reinterpret_cast<const bf8_t*>(xb + (size_t)(m0 + row) * 128 + e0);
    *reinterpret_cast<bf8_t*>(&a_lds[hw]) = xa;
    bf8_t wa = *reinterpret_cast<const bf8_t*>(w + (size_t)(n0 + row) * 128 + e0);
    *reinterpret_cast<bf8_t*>(&b_lds[hw]) = wa;
  }
  __syncthreads();

  const int lane = tid & 63, wid = tid >> 6;
  const int wr = wid >> 1, wc = wid & 1;
  const int g = lane >> 4, c16 = lane & 15;
  f4_t acc[2][2];
#pragma unroll
  for (int a = 0; a < 2; ++a)
#pragma unroll
    for (int b = 0; b < 2; ++b) acc[a][b] = (f4_t)0.0f;

#pragma unroll
  for (int kc = 0; kc < 4; ++kc) {
    bf8_t af[2], bf_[2];
#pragma unroll
    for (int fr = 0; fr < 2; ++fr) {
      int row = wr * 32 + fr * 16 + c16;
      int hw = ((row << 7) | (kc * 32 + g * 8)) ^ ((row & 7) << 3);
      af[fr] = *reinterpret_cast<const bf8_t*>(&a_lds[hw]);
    }
#pragma unroll
    for (int fc = 0; fc < 2; ++fc) {
      int row = wc * 32 + fc * 16 + c16;
      int hw = ((row << 7) | (kc * 32 + g * 8)) ^ ((row & 7) << 3);
      bf_[fc] = *reinterpret_cast<const bf8_t*>(&b_lds[hw]);
    }
#pragma unroll
    for (int fr = 0; fr < 2; ++fr)
#pragma unroll
      for (int fc = 0; fc < 2; ++fc)
        acc[fr][fc] = __builtin_amdgcn_mfma_f32_16x16x32_bf16(af[fr], bf_[fc], acc[fr][fc], 0, 0, 0);
  }

  if (mat == 2) {
    // ---- V: transpose via LDS (stride 72), write vT_g[bh][dv][s] coalesced
    __syncthreads();                      // a_lds reads complete
#pragma unroll
    for (int fr = 0; fr < 2; ++fr)
#pragma unroll
      for (int fc = 0; fc < 2; ++fc)
#pragma unroll
        for (int j = 0; j < 4; ++j) {
          int fcol = wc * 32 + fc * 16 + c16;     // 0..63 (local dv)
          int m = wr * 32 + fr * 16 + g * 4 + j;  // 0..63 (local s)
          a_lds[fcol * 72 + m] = f2bf(acc[fr][fc][j]);
        }
    __syncthreads();
    const int b = mt >> 4, sl0 = m0 & 1023;
    const int hq = nt >> 1, dvb = (nt & 1) * 64;
#pragma unroll
    for (int i = 0; i < 2; ++i) {
      int r = tid >> 2, c0 = ((tid & 3) * 2 + i) * 8;   // r 0..63, c0 0..56
      bf8_t v = *reinterpret_cast<const bf8_t*>(&a_lds[r * 72 + c0]);
      size_t adr = ((size_t)((b * 16 + hq) * 128 + dvb + r)) * 1024 + sl0 + c0;
      *reinterpret_cast<bf8_t*>(vo + adr) = v;
    }
    return;
  }

  // ---- q/k: RoPE epilogue ----
  u16* outp = (mat == 0) ? qo : ko;
#pragma unroll
  for (int fr = 0; fr < 2; ++fr) {
#pragma unroll
    for (int fc = 0; fc < 2; ++fc) {
      int fcol = n0 + wc * 32 + fc * 16 + c16;   // 0..2047
      int h = fcol >> 7, d = fcol & 127, p = d >> 1;
#pragma unroll
      for (int j = 0; j < 4; ++j) {
        int m = m0 + wr * 32 + fr * 16 + g * 4 + j;
        int b = m >> 10, sl = m & 1023;
        float v = acc[fr][fc][j];
        float vx = __shfl_xor(v, 1);
        float cv = cosT[sl * 64 + p], sv = sinT[sl * 64 + p];
        if (!(lane & 1)) {
          float e_out = v * cv - vx * sv;
          float o_out = v * sv + vx * cv;
          u32 u = (u32)f2bf(e_out) | ((u32)f2bf(o_out) << 16);
          u32 elem = ((u32)((b * 16 + h) * 1024 + sl)) * 128 + (u32)d;
          reinterpret_cast<u32*>(outp)[elem >> 1] = u;
        }
      }
    }
  }
}

// ---------------- kernel B: flash attention (round-5 proven, verbatim) -----
// 4 waves x 16 q-rows; qt = 2pp + (wid>>1); T = pp+1 KV tiles of 64. l via
// ones-column (vT row 128). Defer-max guard. 12 waves/CU.
__device__ __forceinline__ void stage_kv(const u16* __restrict__ Kp,
                                         const u16* __restrict__ Vt, int t,
                                         int tid, u16* k_lds, u16* vT) {
#pragma unroll
  for (int i = 0; i < 4; ++i) {
    int n = tid >> 2, c0 = ((tid & 3) * 4 + i) * 8;            // K: 64x128
    bf8_t kv = *reinterpret_cast<const bf8_t*>(Kp + (size_t)(t * 64 + n) * 128 + c0);
    *reinterpret_cast<bf8_t*>(&k_lds[n * 128 + (c0 ^ ((n & 7) << 3))]) = kv;
    int dv = tid >> 1, c1 = ((tid & 1) * 4 + i) * 8;           // vT: 128x64
    bf8_t vv = *reinterpret_cast<const bf8_t*>(Vt + (size_t)dv * 1024 + t * 64 + c1);
    *reinterpret_cast<bf8_t*>(&vT[dv * 72 + c1]) = vv;
  }
}

__global__ __launch_bounds__(256, 3) void attn(
    const u16* __restrict__ qw, const u16* __restrict__ kw,
    const u16* __restrict__ vtg, u16* __restrict__ yw) {
  __shared__ __align__(16) u16 k_lds[64 * 128];       // 16 KB, XOR swizzle
  __shared__ __align__(16) u16 vT[144 * 72];          // 20.25 KB, stride-72 pad
  __shared__ __align__(16) u16 p_lds[4][16 * 64];     // 8 KB, per-wave
  const int tid = threadIdx.x, lane = tid & 63, wid = tid >> 6;
  const int g = lane >> 4, c16 = lane & 15;
  const int bid = blockIdx.x;                  // 0..1023
  const int pp = 15 - (bid >> 6);              // LPT: long blocks first
  const int bh = bid & 63;                     // bid%8 == bh%8 -> same XCD
  const int b = bh >> 4, h = bh & 15;
  const int qt = 2 * pp + (wid >> 1);          // this wave-pair's 32-row q-tile
  const int T = pp + 1;
  const u16* Qp = qw + (size_t)bh * SEQ * DH;
  const u16* Kp = kw + (size_t)bh * SEQ * DH;
  const u16* Vt = vtg + (size_t)bh * DH * SEQ;
  const float kscale = 0.08838834764831845f * 1.4426950408889634f; // rsqrt(128)*log2e
  const int qrow0 = qt * 32 + (wid & 1) * 16;  // wave's 16 q-rows (global)
  const int moff = (wid >> 1) * 32 + (wid & 1) * 16;  // diag-mask offset

  // ones row (dv=128) + zero rows 129..143 (cols 0..63 read)
  {
    int r = 128 + (tid >> 4), c0 = (tid & 15) * 4;
    u16 v = (r == 128) ? (u16)0x3F80 : (u16)0;
#pragma unroll
    for (int e = 0; e < 4; ++e) vT[r * 72 + c0 + e] = v;
  }

  bf8_t qf[4];
#pragma unroll
  for (int c = 0; c < 4; ++c)
    qf[c] = *reinterpret_cast<const bf8_t*>(Qp + (size_t)(qrow0 + c16) * 128 + c * 32 + g * 8);

  f4_t yacc[9];                               // [8] = l (ones-column)
#pragma unroll
  for (int f = 0; f < 9; ++f) yacc[f] = (f4_t)0.0f;
  float m_run[4];
#pragma unroll
  for (int j = 0; j < 4; ++j) m_run[j] = -3e38f;

  stage_kv(Kp, Vt, 0, tid, k_lds, vT);
  __syncthreads();

  for (int t = 0; t < T; ++t) {
    // ---- S = Q K^T ----
    f4_t sf[4];
#pragma unroll
    for (int nf = 0; nf < 4; ++nf) sf[nf] = (f4_t)0.0f;
    __builtin_amdgcn_s_setprio(1);
#pragma unroll
    for (int nf = 0; nf < 4; ++nf) {
      int row = nf * 16 + c16;
#pragma unroll
      for (int kc = 0; kc < 4; ++kc) {
        int hw = ((row << 7) | (kc * 32 + g * 8)) ^ ((row & 7) << 3);
        bf8_t kf = *reinterpret_cast<const bf8_t*>(&k_lds[hw]);
        sf[nf] = __builtin_amdgcn_mfma_f32_16x16x32_bf16(qf[kc], kf, sf[nf], 0, 0, 0);
      }
    }
    __builtin_amdgcn_s_setprio(0);

    // ---- diagonal mask (last tile only) ----
    if (t == T - 1) {
#pragma unroll
      for (int nf = 0; nf < 4; ++nf) {
        int keyc = nf * 16 + c16;
#pragma unroll
        for (int j = 0; j < 4; ++j)
          if (keyc > moff + g * 4 + j) sf[nf][j] = -3e38f;
      }
    }

    // ---- defer-max guard: cross-lane work only when needed (tile 0 + rare)
    int chk = 0;
#pragma unroll
    for (int j = 0; j < 4; ++j) {
      float lmx = fmaxf(fmaxf(sf[0][j], sf[1][j]), fmaxf(sf[2][j], sf[3][j]));
      chk |= (lmx > m_run[j] + 32.0f) ? 1 : 0;
    }
    if (__any(chk)) {
      float lm[4];
#pragma unroll
      for (int j = 0; j < 4; ++j) {
        lm[j] = fmaxf(fmaxf(sf[0][j], sf[1][j]), fmaxf(sf[2][j], sf[3][j]));
        lm[j] = fmaxf(lm[j], __shfl_xor(lm[j], 1));
        lm[j] = fmaxf(lm[j], __shfl_xor(lm[j], 2));
        lm[j] = fmaxf(lm[j], __shfl_xor(lm[j], 4));
        lm[j] = fmaxf(lm[j], __shfl_xor(lm[j], 8));
      }
#pragma unroll
      for (int j = 0; j < 4; ++j) {
        float mn = fmaxf(m_run[j], lm[j]);
        float alpha = exp2f((m_run[j] - mn) * kscale);
        m_run[j] = mn;
#pragma unroll
        for (int f = 0; f < 9; ++f) yacc[f][j] *= alpha;
      }
    }

    // ---- P = exp2((S-m)*ks) -> bf16 -> wave-private p_lds ----
#pragma unroll
    for (int nf = 0; nf < 4; ++nf) {
#pragma unroll
      for (int j = 0; j < 4; ++j) {
        float pv = exp2f((sf[nf][j] - m_run[j]) * kscale);
        int q = g * 4 + j, n = nf * 16 + c16;
        int hw = ((q << 6) | n) ^ ((q & 7) << 3);
        p_lds[wid][hw] = f2bf(pv);
      }
    }
    bf8_t pa[2];
#pragma unroll
    for (int cc = 0; cc < 2; ++cc) {
      int hw = ((c16 << 6) | (cc * 32 + g * 8)) ^ ((c16 & 7) << 3);
      pa[cc] = *reinterpret_cast<const bf8_t*>(&p_lds[wid][hw]);
    }

    // ---- y += P V ; l accumulates via ones-column (f=8) ----
    __builtin_amdgcn_s_setprio(1);
#pragma unroll
    for (int f = 0; f < 9; ++f) {
#pragma unroll
      for (int cc = 0; cc < 2; ++cc) {
        bf8_t vf = *reinterpret_cast<const bf8_t*>(&vT[(f * 16 + c16) * 72 + cc * 32 + g * 8]);
        yacc[f] = __builtin_amdgcn_mfma_f32_16x16x32_bf16(pa[cc], vf, yacc[f], 0, 0, 0);
      }
    }
    __builtin_amdgcn_s_setprio(0);

    __syncthreads();                     // everyone done reading k/vT
    if (t + 1 < T) {
      stage_kv(Kp, Vt, t + 1, tid, k_lds, vT);
      __syncthreads();
    }
  }

  // ---- epilogue: l broadcast from c16==0 lane; y /= l; store bf16 ----
  float rl[4];
#pragma unroll
  for (int j = 0; j < 4; ++j) {
    float lv = __shfl(yacc[8][j], lane & 48);
    rl[j] = 1.0f / lv;
  }
#pragma unroll
  for (int f = 0; f < 8; ++f) {
#pragma unroll
    for (int j = 0; j < 4; ++j) {
      float yv = yacc[f][j] * rl[j];
      float yn = __shfl_xor(yv, 1);
      if (!(lane & 1)) {
        int s_ = qrow0 + g * 4 + j;
        int dv = f * 16 + c16;
        u32 u = (u32)f2bf(yv) | ((u32)f2bf(yn) << 16);
        u32 elem = ((u32)(b * 1024 + s_)) * 2048 + (u32)(h * 128 + dv);
        reinterpret_cast<u32*>(yw)[elem >> 1] = u;
      }
    }
  }
}

// ---------------- kernel C: output projection (split-K=2, atomic) ----------
__global__ __launch_bounds__(256) void oproj(
    const u16* __restrict__ yw, const u16* __restrict__ wob,
    float* __restrict__ out) {
  __shared__ __align__(16) u16 a_lds[64 * 64];
  __shared__ __align__(16) u16 b_lds[64 * 64];
  const int tid = threadIdx.x, lane = tid & 63, wid = tid >> 6;
  const int g = lane >> 4, c16 = lane & 15;
  const int wr = wid >> 1, wc = wid & 1;
  const int m0 = blockIdx.x * 64, n0 = blockIdx.y * 64;
  const int z = blockIdx.z;
  f4_t acc[2][2];
#pragma unroll
  for (int a = 0; a < 2; ++a)
#pragma unroll
    for (int b = 0; b < 2; ++b) acc[a][b] = (f4_t)0.0f;

  for (int kt = z * 16; kt < z * 16 + 16; ++kt) {
    int kb = kt * 64;
#pragma unroll
    for (int i = 0; i < 2; ++i) {
      int idx = tid + i * 256;            // 0..511
      int row = idx >> 3, k0 = (idx & 7) * 8;
      int hw = ((row << 6) | k0) ^ ((row & 7) << 3);
      bf8_t av = *reinterpret_cast<const bf8_t*>(yw + (size_t)(m0 + row) * 2048 + kb + k0);
      *reinterpret_cast<bf8_t*>(&a_lds[hw]) = av;
      bf8_t bv = *reinterpret_cast<const bf8_t*>(wob + (size_t)(n0 + row) * 2048 + kb + k0);
      *reinterpret_cast<bf8_t*>(&b_lds[hw]) = bv;
    }
    __syncthreads();
#pragma unroll
    for (int c = 0; c < 2; ++c) {
      bf8_t af[2], bf_[2];
#pragma unroll
      for (int fr = 0; fr < 2; ++fr) {
        int row = wr * 32 + fr * 16 + c16;
        int hw = ((row << 6) | (c * 32 + g * 8)) ^ ((row & 7) << 3);
        af[fr] = *reinterpret_cast<const bf8_t*>(&a_lds[hw]);
      }
#pragma unroll
      for (int fc = 0; fc < 2; ++fc) {
        int row = wc * 32 + fc * 16 + c16;
        int hw = ((row << 6) | (c * 32 + g * 8)) ^ ((row & 7) << 3);
        bf_[fc] = *reinterpret_cast<const bf8_t*>(&b_lds[hw]);
      }
#pragma unroll
      for (int fr = 0; fr < 2; ++fr)
#pragma unroll
        for (int fc = 0; fc < 2; ++fc)
          acc[fr][fc] = __builtin_amdgcn_mfma_f32_16x16x32_bf16(af[fr], bf_[fc], acc[fr][fc], 0, 0, 0);
    }
    __syncthreads();
  }
#pragma unroll
  for (int fr = 0; fr < 2; ++fr)
#pragma unroll
    for (int fc = 0; fc < 2; ++fc)
#pragma unroll
      for (int j = 0; j < 4; ++j) {
        int m = m0 + wr * 32 + fr * 16 + g * 4 + j;
        int e = n0 + wc * 32 + fc * 16 + c16;
        atomicAdd(&out[(size_t)m * 128 + e], acc[fr][fc][j]);  // 2 addends: exact
      }
}

// ---------------------------------------------------------------------------
extern "C" void kernel_launch(void* const* d_in, const int* in_sizes, int n_in,
                              void* d_out, int out_size, void* d_ws, size_t ws_size,
                              hipStream_t stream) {
  const float* x  = (const float*)d_in[0];
  const float* wq = (const float*)d_in[1];
  const float* wk = (const float*)d_in[2];
  const float* wv = (const float*)d_in[3];
  const float* wo = (const float*)d_in[4];
  float* out = (float*)d_out;

  char* ws = (char*)d_ws;
  const size_t NEED = (512ull << 10) + 4ull * (16ull << 20) + (3ull << 20);
  if (ws_size < NEED) return;
  float* cosT = (float*)ws;
  float* sinT = cosT + 64 * 1024;
  u16* qws = (u16*)(ws + (512 << 10));
  u16* kws = qws + (8u << 20);
  u16* vws = kws + (8u << 20);      // vT_g[bh][dv][s]
  u16* yws = vws + (8u << 20);
  u16* xb  = yws + (8u << 20);
  u16* wqb = xb  + (1u << 19);
  u16* wkb = wqb + (1u << 18);
  u16* wvb = wkb + (1u << 18);
  u16* wob = wvb + (1u << 18);

  hipMemsetAsync(d_out, 0, (size_t)out_size * sizeof(float), stream);
  to_bf16<<<768, 256, 0, stream>>>(x, wq, wk, wv, wo, xb, wqb, wkb, wvb, wob);
  rope_tables<<<256, 256, 0, stream>>>(cosT, sinT);
  qkv_rope<<<dim3(64, 96), 256, 0, stream>>>(xb, wqb, wkb, wvb, cosT, sinT, qws, kws, vws);
  attn<<<1024, 256, 0, stream>>>(qws, kws, vws, yws);
  oproj<<<dim3(64, 2, 2), 256, 0, stream>>>(yws, wob, out);
}